// Round 1
// baseline (240.498 us; speedup 1.0000x reference)
//
#include <hip/hip_runtime.h>
#include <math.h>

typedef int v4i  __attribute__((ext_vector_type(4)));
typedef int v16i __attribute__((ext_vector_type(16)));

#define DIM 4096
#define BT 128
#define KT 128          // K-tile bytes (int8)
#define TILE (BT * KT)  // 16384 B per A/B tile

// ---------------------------------------------------------------------------
// async global->LDS 16B copy (wave-uniform base + lane*16 destination rule)
// ---------------------------------------------------------------------------
__device__ __forceinline__ void async16(const void* g, void* l) {
    __builtin_amdgcn_global_load_lds((__attribute__((address_space(1))) void*)(g),
                                     (__attribute__((address_space(3))) void*)(l),
                                     16, 0, 0);
}

// raw barrier / counted waitcnt: NO implicit vmcnt(0) drain (T4).
// "memory" clobber pins all memory ops (loads, ds_reads, global_load_lds)
// on their side of the asm; register-only MFMAs may drift, which is safe.
#define VMCNT(N) asm volatile("s_waitcnt vmcnt(" #N ")" ::: "memory")
#define BARRIER() asm volatile("s_barrier" ::: "memory")

// ---------------------------------------------------------------------------
// Fused prep (unchanged, verified): blocks [0,4096) FWHT(256)+int4 quant;
// blocks [4096,20480) narrow int32 weights to int8.
// ---------------------------------------------------------------------------
__global__ __launch_bounds__(256) void prep(const float* __restrict__ x,
                                            const int* __restrict__ w,
                                            signed char* __restrict__ q,
                                            signed char* __restrict__ w8,
                                            float* __restrict__ scales) {
    if (blockIdx.x >= 4096) {
        int i = (blockIdx.x - 4096) * 256 + threadIdx.x;
        int4 v = ((const int4*)w)[i];
        char4 c;
        c.x = (signed char)v.x; c.y = (signed char)v.y;
        c.z = (signed char)v.z; c.w = (signed char)v.w;
        ((char4*)w8)[i] = c;
        return;
    }
    const int row  = blockIdx.x;
    const int lane = threadIdx.x & 63;
    const int wave = threadIdx.x >> 6;
    const float4* xr4 = (const float4*)(x + (size_t)row * DIM);

    float sgn[6];
    #pragma unroll
    for (int i = 0; i < 6; ++i) sgn[i] = (lane & (1 << i)) ? -1.0f : 1.0f;

    float f[4][4];
    #pragma unroll
    for (int b = 0; b < 4; ++b) {
        const int blk = wave + 4 * b;
        float4 v = xr4[blk * 64 + lane];
        float t0 = v.x + v.y, t1 = v.x - v.y;
        float t2 = v.z + v.w, t3 = v.z - v.w;
        f[b][0] = t0 + t2; f[b][1] = t1 + t3;
        f[b][2] = t0 - t2; f[b][3] = t1 - t3;
        #pragma unroll
        for (int st = 0; st < 6; ++st) {
            const int m = 1 << st;
            #pragma unroll
            for (int j = 0; j < 4; ++j) {
                float p = __shfl_xor(f[b][j], m, 64);
                f[b][j] = fmaf(sgn[st], f[b][j], p);
            }
        }
        #pragma unroll
        for (int j = 0; j < 4; ++j) f[b][j] *= 0.0625f;   // / sqrt(256)
    }

    float m = 0.0f;
    #pragma unroll
    for (int b = 0; b < 4; ++b)
        #pragma unroll
        for (int j = 0; j < 4; ++j) m = fmaxf(m, fabsf(f[b][j]));
    #pragma unroll
    for (int d = 32; d; d >>= 1) m = fmaxf(m, __shfl_xor(m, d, 64));
    __shared__ float sm[4];
    if (lane == 0) sm[wave] = m;
    __syncthreads();
    m = fmaxf(fmaxf(sm[0], sm[1]), fmaxf(sm[2], sm[3]));

    const float s = m / 7.0f;                 // exact-match reference scale
    if (threadIdx.x == 0) scales[row] = s;

    char4* qr4 = (char4*)(q + (size_t)row * DIM);
    #pragma unroll
    for (int b = 0; b < 4; ++b) {
        const int blk = wave + 4 * b;
        char4 c;
        int qi;
        qi = (int)rintf(f[b][0] / s); c.x = (signed char)min(7, max(-8, qi));
        qi = (int)rintf(f[b][1] / s); c.y = (signed char)min(7, max(-8, qi));
        qi = (int)rintf(f[b][2] / s); c.z = (signed char)min(7, max(-8, qi));
        qi = (int)rintf(f[b][3] / s); c.w = (signed char)min(7, max(-8, qi));
        qr4[blk * 64 + lane] = c;
    }
}

// ---------------------------------------------------------------------------
// int8 GEMM, double-buffered LDS, counted-vmcnt pipeline (T4) + setprio (T5)
// + 2D XCD-aware block swizzle (T1).
//
// Per K-tile:  STAGE(t+1 -> buf^1)         (8 global_load_lds, stay in flight)
//              s_waitcnt vmcnt(8)          (tile t landed; t+1 NOT drained)
//              s_barrier                   (raw -- no implicit vmcnt(0))
//              setprio(1) COMPUTE(buf t&1) setprio(0)
//              s_barrier                   (readers done before buf^1 reuse)
// This keeps 8 loads in flight across every barrier -- the AITER/HK property
// the old __syncthreads() (vmcnt(0)+lgkmcnt(0) drain) destroyed.
// S layout: [A0 | B0 | A1 | B1], 16 KB each (64 KB total, 2 blocks/CU).
// ---------------------------------------------------------------------------
__global__ __launch_bounds__(256) void gemm_q8(const signed char* __restrict__ A,
                                               const signed char* __restrict__ B,
                                               const float* __restrict__ rowScale,
                                               const float* __restrict__ wscale,
                                               const float* __restrict__ bias,
                                               float* __restrict__ out) {
    __shared__ __align__(16) signed char S[4 * TILE];   // 64 KB

    // T1: 2D XCD swizzle. flat id -> (xcd = flat&7, i = flat>>3).
    // XCD x owns an 8(bm) x 16(bn) rectangle: bm = (x>>1)*8 + (i&7),
    // bn = (x&1)*16 + (i>>3). Bijective since 1024 % 8 == 0.
    const int flat = blockIdx.y * gridDim.x + blockIdx.x;
    const int xcd  = flat & 7;
    const int idx  = flat >> 3;
    const int bm   = ((xcd >> 1) << 3) + (idx & 7);
    const int bn   = ((xcd & 1) << 4) + (idx >> 3);

    const int t = threadIdx.x;
    const int lane = t & 63, wave = t >> 6;
    const int wm = (wave >> 1) * 64, wn = (wave & 1) * 64;
    const int l31 = lane & 31, lh = lane >> 5;

    // running global staging pointers (advance KT per staged tile)
    const signed char* ga[4];
    const signed char* gb[4];
    #pragma unroll
    for (int h = 0; h < 4; ++h) {
        const int cidx = t + 256 * h;             // 0..1023
        const int row  = cidx >> 3;               // 0..127
        const int g    = (cidx & 7) ^ (row & 7);  // swizzled global chunk
        ga[h] = A + (size_t)(bm * BT + row) * DIM + g * 16;
        gb[h] = B + (size_t)(bn * BT + row) * DIM + g * 16;
    }

    // loop-invariant per-lane LDS byte offsets (buffer selected by imm const)
    int offA[2][4], offB[2][4];
    #pragma unroll
    for (int i = 0; i < 2; ++i)
        #pragma unroll
        for (int s = 0; s < 4; ++s) {
            const int r  = wm + i * 32 + l31;
            const int c  = wn + i * 32 + l31;
            const int cl = 2 * s + lh;            // logical 16B chunk (k-step s)
            offA[i][s] = r * KT + ((cl ^ (r & 7)) * 16);
            offB[i][s] = c * KT + ((cl ^ (c & 7)) * 16) + TILE;
        }

    v16i acc[2][2] = {};

#define STAGE(P) do {                                                          \
        _Pragma("unroll")                                                      \
        for (int h = 0; h < 4; ++h) {                                          \
            const int l = (P) * 2 * TILE + (t + 256 * h) * 16;                 \
            async16(ga[h], &S[l]);        ga[h] += KT;                         \
            async16(gb[h], &S[l + TILE]); gb[h] += KT;                         \
        }                                                                      \
    } while (0)

#define COMPUTE(P) do {                                                        \
        __builtin_amdgcn_s_setprio(1);                                         \
        _Pragma("unroll")                                                      \
        for (int s = 0; s < 4; ++s) {                                          \
            const v4i a0 = *(const v4i*)&S[(P) * 2 * TILE + offA[0][s]];       \
            const v4i a1 = *(const v4i*)&S[(P) * 2 * TILE + offA[1][s]];       \
            const v4i b0 = *(const v4i*)&S[(P) * 2 * TILE + offB[0][s]];       \
            const v4i b1 = *(const v4i*)&S[(P) * 2 * TILE + offB[1][s]];       \
            acc[0][0] = __builtin_amdgcn_mfma_i32_32x32x32_i8(a0, b0, acc[0][0], 0, 0, 0); \
            acc[0][1] = __builtin_amdgcn_mfma_i32_32x32x32_i8(a0, b1, acc[0][1], 0, 0, 0); \
            acc[1][0] = __builtin_amdgcn_mfma_i32_32x32x32_i8(a1, b0, acc[1][0], 0, 0, 0); \
            acc[1][1] = __builtin_amdgcn_mfma_i32_32x32x32_i8(a1, b1, acc[1][1], 0, 0, 0); \
        }                                                                      \
        __builtin_amdgcn_s_setprio(0);                                         \
    } while (0)

    // 32 K-tiles, tile t -> buf t&1. Counted-vmcnt steady state:
    //   STAGE(t+1); vmcnt(8) [t landed, t+1 in flight]; bar; COMPUTE(t); bar;
    STAGE(0);                                  // tile 0 -> buf0
    #pragma unroll 1
    for (int it = 0; it < 15; ++it) {
        STAGE(1); VMCNT(8); BARRIER();         // stage 2it+1, tile 2it ready
        COMPUTE(0);                            // compute 2it
        BARRIER();                             // buf1 readers?? no: buf0 done; guards buf0 reuse next iter? -> guards STAGE into buf that was just read NEXT
        STAGE(0); VMCNT(8); BARRIER();         // stage 2it+2, tile 2it+1 ready
        COMPUTE(1);                            // compute 2it+1
        BARRIER();                             // all waves done reading buf1 before next STAGE(1)
    }
    STAGE(1); VMCNT(8); BARRIER();             // stage tile 31, tile 30 ready
    COMPUTE(0);                                // compute tile 30
    BARRIER();
    VMCNT(0); BARRIER();                       // tile 31 landed everywhere
    COMPUTE(1);                                // compute tile 31

#undef STAGE
#undef COMPUTE

    // epilogue: out[n,o] = acc * sx[n] * ws[o] + bias[o]
    // C/D: col = lane&31, row = (reg&3) + 8*(reg>>2) + 4*(lane>>5)  [m74/m101]
    #pragma unroll
    for (int j = 0; j < 2; ++j) {
        const int col = bn * BT + wn + j * 32 + l31;
        const float ws = wscale[col];
        const float bs = bias[col];
        #pragma unroll
        for (int i = 0; i < 2; ++i) {
            const int rb = bm * BT + wm + i * 32 + 4 * lh;
            #pragma unroll
            for (int r = 0; r < 16; ++r) {
                const int row = rb + (r & 3) + 8 * (r >> 2);
                out[(size_t)row * DIM + col] =
                    ((float)acc[i][j][r] * rowScale[row]) * ws + bs;
            }
        }
    }
}

// ---------------------------------------------------------------------------
extern "C" void kernel_launch(void* const* d_in, const int* in_sizes, int n_in,
                              void* d_out, int out_size, void* d_ws, size_t ws_size,
                              hipStream_t stream) {
    const float* x      = (const float*)d_in[0];
    const int*   wint   = (const int*)d_in[1];
    const float* wscale = (const float*)d_in[2];
    const float* bias   = (const float*)d_in[3];
    float* out = (float*)d_out;

    signed char* q8 = (signed char*)d_ws;                         // 16 MB
    signed char* w8 = q8 + (size_t)DIM * DIM;                     // 16 MB
    float* sx = (float*)(w8 + (size_t)DIM * DIM);                 // 16 KB

    prep<<<4096 + 16384, 256, 0, stream>>>(x, wint, q8, w8, sx);
    gemm_q8<<<dim3(DIM / BT, DIM / BT), 256, 0, stream>>>(q8, w8, sx, wscale, bias, out);
}